// Round 1
// baseline (1429.876 us; speedup 1.0000x reference)
//
#include <hip/hip_runtime.h>
#include <math.h>

// ---------------------------------------------------------------------------
// GatedAttentionTransformer  (B=2, T=2048, D=1024, E=2048, S=128, L=4, V=32000)
// Round 0: f16-MFMA pipeline, f32 accumulation + f32 residual stream.
//   - one m97-style GEMM template (128x128 tile, BK=32, global_load_lds),
//     epilogues: plain f32 / silu->f16 / scores(scale,causal,relu^2)->f16 /
//     residual-add f32
//   - weights transposed+converted to f16 (N x K) once per call
//   - causal: scores skips upper blocks, av caps K at (rowblk+1)*128
// ---------------------------------------------------------------------------

#define Bz 2
#define Tt 2048
#define Dd 1024
#define Ee 2048
#define Ss 128
#define Ll 4
#define Vv 32000
#define BT (Bz * Tt)   // 4096

typedef __attribute__((ext_vector_type(8))) _Float16 f16x8;
typedef __attribute__((ext_vector_type(4))) _Float16 f16x4;
typedef __attribute__((ext_vector_type(4))) float    f32x4;

__device__ __forceinline__ void load_lds16(const void* g, void* l) {
  // async global->LDS, 16B per lane; LDS dest is wave-uniform base + lane*16
  __builtin_amdgcn_global_load_lds(
      (const __attribute__((address_space(1))) void*)g,
      (__attribute__((address_space(3))) void*)l, 16, 0, 0);
}

#define BM 128
#define BN 128
#define BK 32

enum { EPI_F32 = 0, EPI_SILU = 1, EPI_SCORES = 2, EPI_RESID = 3 };

// C = A(MxK, lda) * Bt(NxK, ldb)^T ; f32 accum; per-z pointer strides (elements)
template <int EPI>
__global__ void __launch_bounds__(256, 2) gemm_bt(
    const _Float16* __restrict__ A, long sA,
    const _Float16* __restrict__ Bt, long sB,
    void* __restrict__ Cp, long sC,
    int M, int N, int K, int lda, int ldb, int ldc, int causal) {
  int bm = blockIdx.x, bn = blockIdx.y, bz = blockIdx.z;
  if (EPI == EPI_SCORES && bn > bm) return;  // strictly above causal diagonal
  A += (size_t)bz * sA;
  Bt += (size_t)bz * sB;

  int Keff = K;
  if (causal == 2) {  // av GEMM: keys beyond this row block are zero
    int km = (bm + 1) * BM;
    Keff = km < K ? km : K;
  }

  __shared__ __align__(16) _Float16 As[BM * BK];
  __shared__ __align__(16) _Float16 Bs[BN * BK];

  int tid = threadIdx.x;
  int lane = tid & 63, wave = tid >> 6;
  int wr = (wave >> 1) << 6;  // wave row offset (2x2 wave grid, 64x64 each)
  int wc = (wave & 1) << 6;
  int row0 = bm * BM, col0 = bn * BN;
  int fr = lane & 15;          // fragment row (A) / col (B) / col (C)
  int kg = lane >> 4;          // k-group 0..3
  int srow = lane >> 2;        // staging: row within 16-row chunk
  int scol = (lane & 3) << 3;  // staging: f16 col offset (16B granules)

  f32x4 acc[4][4];
#pragma unroll
  for (int i = 0; i < 4; i++)
#pragma unroll
    for (int j = 0; j < 4; j++)
#pragma unroll
      for (int e = 0; e < 4; e++) acc[i][j][e] = 0.f;

  const f16x8* As8 = (const f16x8*)As;
  const f16x8* Bs8 = (const f16x8*)Bs;

  for (int k0 = 0; k0 < Keff; k0 += BK) {
    __syncthreads();  // previous compute done before overwrite
#pragma unroll
    for (int i = 0; i < 2; i++) {
      int rb = (wave * 2 + i) * 16;  // 16-row (1024B) chunk
      load_lds16(A + (size_t)(row0 + rb + srow) * lda + k0 + scol,
                 (void*)&As[rb * BK]);
      load_lds16(Bt + (size_t)(col0 + rb + srow) * ldb + k0 + scol,
                 (void*)&Bs[rb * BK]);
    }
    asm volatile("s_waitcnt vmcnt(0)" ::: "memory");
    __syncthreads();

    f16x8 af[4], bf[4];
#pragma unroll
    for (int m = 0; m < 4; m++)
      af[m] = As8[(size_t)(wr + m * 16 + fr) * (BK / 8) + kg];
#pragma unroll
    for (int n = 0; n < 4; n++)
      bf[n] = Bs8[(size_t)(wc + n * 16 + fr) * (BK / 8) + kg];
#pragma unroll
    for (int m = 0; m < 4; m++)
#pragma unroll
      for (int n = 0; n < 4; n++)
        acc[m][n] =
            __builtin_amdgcn_mfma_f32_16x16x32_f16(af[m], bf[n], acc[m][n], 0, 0, 0);
  }

  // epilogue: C/D layout col=lane&15, row=(lane>>4)*4+reg  [m89-verified]
#pragma unroll
  for (int m = 0; m < 4; m++) {
    int gr0 = row0 + wr + m * 16 + (kg << 2);
#pragma unroll
    for (int n = 0; n < 4; n++) {
      int gc = col0 + wc + n * 16 + fr;
#pragma unroll
      for (int r = 0; r < 4; r++) {
        float v = acc[m][n][r];
        size_t ci = (size_t)(gr0 + r) * ldc + gc;
        if (EPI == EPI_F32) {
          ((float*)Cp + (size_t)bz * sC)[ci] = v;
        } else if (EPI == EPI_SILU) {
          ((_Float16*)Cp + (size_t)bz * sC)[ci] =
              (_Float16)(v / (1.f + expf(-v)));
        } else if (EPI == EPI_SCORES) {
          float s = v * 0.08838834764831845f;  // 1/sqrt(128)
          s = fmaxf(s, 0.f);
          s = (gc <= gr0 + r) ? s * s : 0.f;   // causal mask then relu^2
          ((_Float16*)Cp + (size_t)bz * sC)[ci] = (_Float16)s;
        } else {  // EPI_RESID: x += gated @ Wo
          ((float*)Cp)[ci] += v;
        }
      }
    }
  }
}

__global__ void __launch_bounds__(256) ln_kernel(const float* __restrict__ x,
                                                 const float* __restrict__ g,
                                                 const float* __restrict__ b,
                                                 _Float16* __restrict__ out) {
  int row = blockIdx.x, tid = threadIdx.x;
  float4 v = ((const float4*)(x + (size_t)row * Dd))[tid];
  float s = v.x + v.y + v.z + v.w;
  float q = v.x * v.x + v.y * v.y + v.z * v.z + v.w * v.w;
#pragma unroll
  for (int off = 32; off > 0; off >>= 1) {
    s += __shfl_down(s, off, 64);
    q += __shfl_down(q, off, 64);
  }
  __shared__ float ss[4], sq[4];
  int lane = tid & 63, wv = tid >> 6;
  if (lane == 0) { ss[wv] = s; sq[wv] = q; }
  __syncthreads();
  s = ss[0] + ss[1] + ss[2] + ss[3];
  q = sq[0] + sq[1] + sq[2] + sq[3];
  float mu = s * (1.f / Dd);
  float var = q * (1.f / Dd) - mu * mu;
  float rs = rsqrtf(var + 1e-5f);
  float4 gg = ((const float4*)g)[tid];
  float4 bb = ((const float4*)b)[tid];
  f16x4 o;
  o[0] = (_Float16)((v.x - mu) * rs * gg.x + bb.x);
  o[1] = (_Float16)((v.y - mu) * rs * gg.y + bb.y);
  o[2] = (_Float16)((v.z - mu) * rs * gg.z + bb.z);
  o[3] = (_Float16)((v.w - mu) * rs * gg.w + bb.w);
  ((f16x4*)(out + (size_t)row * Dd))[tid] = o;
}

__global__ void embed_kernel(const int* __restrict__ toks,
                             const float* __restrict__ emb,
                             float* __restrict__ x) {
  int row = blockIdx.x, tid = threadIdx.x;
  long t = toks[row];
  ((float4*)(x + (size_t)row * Dd))[tid] =
      ((const float4*)(emb + (size_t)t * Dd))[tid];
}

__global__ void rope_table_kernel(float* __restrict__ cosT,
                                  float* __restrict__ sinT) {
  int idx = blockIdx.x * 256 + threadIdx.x;  // T*64
  int t = idx >> 6, i = idx & 63;
  float inv = powf(10000.f, (float)(2 * i) * (-1.f / 128.f));
  float a = (float)t * inv;
  cosT[idx] = cosf(a);
  sinT[idx] = sinf(a);
}

__global__ void rope_kernel(const float* __restrict__ pre,
                            _Float16* __restrict__ o16,
                            const float* __restrict__ cosT,
                            const float* __restrict__ sinT) {
  int row = blockIdx.x * 4 + threadIdx.y;
  int i = threadIdx.x;          // 0..63
  int z = blockIdx.y;           // 0 = q, 1 = k
  const float* p = pre + (size_t)z * BT * Ss + (size_t)row * Ss;
  _Float16* o = o16 + (size_t)z * BT * Ss + (size_t)row * Ss;
  int t = row & (Tt - 1);
  float c = cosT[t * 64 + i], sn = sinT[t * 64 + i];
  float x1 = p[i], x2 = p[i + 64];
  o[i] = (_Float16)(x1 * c - x2 * sn);
  o[i + 64] = (_Float16)(x1 * sn + x2 * c);
}

__global__ void gated_kernel(const _Float16* __restrict__ u,
                             const float* __restrict__ av,
                             _Float16* __restrict__ g) {
  size_t i = ((size_t)blockIdx.x * 256 + threadIdx.x) * 4;
  f16x4 uu = *(const f16x4*)(u + i);
  float4 aa = *(const float4*)(av + i);
  f16x4 o;
  o[0] = (_Float16)((float)uu[0] * aa.x);
  o[1] = (_Float16)((float)uu[1] * aa.y);
  o[2] = (_Float16)((float)uu[2] * aa.z);
  o[3] = (_Float16)((float)uu[3] * aa.w);
  *(f16x4*)(g + i) = o;
}

// out(C x R) = transpose(in(R x C)), convert to f16. 64x64 tiles, LDS pad +1.
template <typename TIn>
__global__ void transconv_kernel(const TIn* __restrict__ in,
                                 _Float16* __restrict__ out, int R, int C,
                                 long s_in, long s_out) {
  __shared__ float tile[64][65];
  in += (size_t)blockIdx.z * s_in;
  out += (size_t)blockIdx.z * s_out;
  int r0 = blockIdx.y * 64, c0 = blockIdx.x * 64;
  int tx = threadIdx.x & 63, ty = threadIdx.x >> 6;
#pragma unroll
  for (int p = 0; p < 16; p++) {
    int r = p * 4 + ty;
    tile[r][tx] = (float)in[(size_t)(r0 + r) * C + c0 + tx];
  }
  __syncthreads();
#pragma unroll
  for (int p = 0; p < 16; p++) {
    int r = p * 4 + ty;
    out[(size_t)(c0 + r) * R + r0 + tx] = (_Float16)tile[tx][r];
  }
}

extern "C" void kernel_launch(void* const* d_in, const int* in_sizes, int n_in,
                              void* d_out, int out_size, void* d_ws,
                              size_t ws_size, hipStream_t stream) {
  const int*   tokens = (const int*)d_in[0];
  const float* emb    = (const float*)d_in[1];
  const float* Wu     = (const float*)d_in[2];
  const float* Wv     = (const float*)d_in[3];
  const float* Wq     = (const float*)d_in[4];
  const float* Wk     = (const float*)d_in[5];
  const float* Wo     = (const float*)d_in[6];
  const float* ln_g   = (const float*)d_in[7];
  const float* ln_b   = (const float*)d_in[8];
  const float* lnf_g  = (const float*)d_in[9];
  const float* lnf_b  = (const float*)d_in[10];
  const float* Wlm    = (const float*)d_in[11];
  float* out = (float*)d_out;
  (void)in_sizes; (void)n_in; (void)out_size;

  char* wsp = (char*)d_ws;
  size_t off = 0;
  auto alloc = [&](size_t bytes) -> void* {
    void* p = wsp + off;
    off = (off + bytes + 255) & ~(size_t)255;
    return p;
  };

  float*    x     = (float*)alloc((size_t)BT * Dd * 4);
  _Float16* xn    = (_Float16*)alloc((size_t)BT * Dd * 2);
  _Float16* uvh   = (_Float16*)alloc((size_t)2 * BT * Ee * 2);      // u | v (silu'd)
  _Float16* vT    = (_Float16*)alloc((size_t)Bz * Ee * Tt * 2);     // v^T per batch
  float*    qkpre = (float*)alloc((size_t)2 * BT * Ss * 4);
  _Float16* qkh   = (_Float16*)alloc((size_t)2 * BT * Ss * 2);      // rope'd q | k
  _Float16* attn  = (_Float16*)alloc((size_t)Bz * Tt * Tt * 2);
  float*    av    = (float*)alloc((size_t)BT * Ee * 4);
  _Float16* gh    = (_Float16*)alloc((size_t)BT * Ee * 2);          // u*av
  float*    cosT  = (float*)alloc((size_t)Tt * 64 * 4);
  float*    sinT  = (float*)alloc((size_t)Tt * 64 * 4);
  _Float16* WuvT  = (_Float16*)alloc((size_t)2 * Ll * Ee * Dd * 2); // E x D
  _Float16* WqkT  = (_Float16*)alloc((size_t)2 * Ll * Ss * Ee * 2); // S x E
  _Float16* WoT   = (_Float16*)alloc((size_t)Ll * Dd * Ee * 2);     // D x E
  _Float16* WlmT  = (_Float16*)alloc((size_t)Vv * Dd * 2);          // V x D
  if (off > ws_size) return;  // workspace too small -> visible as stub-like absmax

  // --- weight transpose+convert (f32 NK -> f16 KN^T) ---
  transconv_kernel<float><<<dim3(Ee / 64, Dd / 64, Ll), 256, 0, stream>>>(
      Wu, WuvT, Dd, Ee, (long)Dd * Ee, (long)Ee * Dd);
  transconv_kernel<float><<<dim3(Ee / 64, Dd / 64, Ll), 256, 0, stream>>>(
      Wv, WuvT + (size_t)Ll * Ee * Dd, Dd, Ee, (long)Dd * Ee, (long)Ee * Dd);
  transconv_kernel<float><<<dim3(Ss / 64, Ee / 64, Ll), 256, 0, stream>>>(
      Wq, WqkT, Ee, Ss, (long)Ee * Ss, (long)Ss * Ee);
  transconv_kernel<float><<<dim3(Ss / 64, Ee / 64, Ll), 256, 0, stream>>>(
      Wk, WqkT + (size_t)Ll * Ss * Ee, Ee, Ss, (long)Ee * Ss, (long)Ss * Ee);
  transconv_kernel<float><<<dim3(Dd / 64, Ee / 64, Ll), 256, 0, stream>>>(
      Wo, WoT, Ee, Dd, (long)Ee * Dd, (long)Dd * Ee);
  transconv_kernel<float><<<dim3(Vv / 64, Dd / 64, 1), 256, 0, stream>>>(
      Wlm, WlmT, Dd, Vv, 0, 0);

  rope_table_kernel<<<(Tt * 64) / 256, 256, 0, stream>>>(cosT, sinT);
  embed_kernel<<<BT, 256, 0, stream>>>(tokens, emb, x);

  for (int l = 0; l < Ll; l++) {
    ln_kernel<<<BT, 256, 0, stream>>>(x, ln_g + (size_t)l * Dd,
                                      ln_b + (size_t)l * Dd, xn);
    // u = silu(xn@Wu), v = silu(xn@Wv)   (z: 0=u, 1=v)
    gemm_bt<EPI_SILU><<<dim3(BT / BM, Ee / BN, 2), 256, 0, stream>>>(
        xn, 0, WuvT + (size_t)l * Ee * Dd, (long)Ll * Ee * Dd, (void*)uvh,
        (long)BT * Ee, BT, Ee, Dd, Dd, Dd, Ee, 0);
    // q_pre = u@Wq, k_pre = v@Wk   (z: 0=q, 1=k)
    gemm_bt<EPI_F32><<<dim3(BT / BM, Ss / BN, 2), 256, 0, stream>>>(
        uvh, (long)BT * Ee, WqkT + (size_t)l * Ss * Ee, (long)Ll * Ss * Ee,
        (void*)qkpre, (long)BT * Ss, BT, Ss, Ee, Ee, Ee, Ss, 0);
    rope_kernel<<<dim3(BT / 4, 2), dim3(64, 4), 0, stream>>>(qkpre, qkh, cosT,
                                                             sinT);
    // v^T per batch for av GEMM
    transconv_kernel<_Float16><<<dim3(Ee / 64, Tt / 64, Bz), 256, 0, stream>>>(
        uvh + (size_t)BT * Ee, vT, Tt, Ee, (long)Tt * Ee, (long)Ee * Tt);
    // scores = relu(mask(q@k^T * scale))^2   (per batch)
    gemm_bt<EPI_SCORES><<<dim3(Tt / BM, Tt / BN, Bz), 256, 0, stream>>>(
        qkh, (long)Tt * Ss, qkh + (size_t)BT * Ss, (long)Tt * Ss, (void*)attn,
        (long)Tt * Tt, Tt, Tt, Ss, Ss, Ss, Tt, 0);
    // av = attn @ v   (per batch, K capped causally)
    gemm_bt<EPI_F32><<<dim3(Tt / BM, Ee / BN, Bz), 256, 0, stream>>>(
        attn, (long)Tt * Tt, vT, (long)Ee * Tt, (void*)av, (long)Tt * Ee, Tt,
        Ee, Tt, Tt, Tt, Ee, 2);
    gated_kernel<<<(BT * Ee / 4) / 256, 256, 0, stream>>>(uvh, av, gh);
    // x += (u*av) @ Wo
    gemm_bt<EPI_RESID><<<dim3(BT / BM, Dd / BN, 1), 256, 0, stream>>>(
        gh, 0, WoT + (size_t)l * Dd * Ee, 0, (void*)x, 0, BT, Dd, Ee, Ee, Ee,
        Dd, 0);
  }

  ln_kernel<<<BT, 256, 0, stream>>>(x, lnf_g, lnf_b, xn);
  gemm_bt<EPI_F32><<<dim3(BT / BM, Vv / BN, 1), 256, 0, stream>>>(
      xn, 0, WlmT, 0, (void*)out, 0, BT, Vv, Dd, Dd, Dd, Vv, 0);
}

// Round 2
// 1389.314 us; speedup vs baseline: 1.0292x; 1.0292x over previous
//
#include <hip/hip_runtime.h>
#include <math.h>

// ---------------------------------------------------------------------------
// GatedAttentionTransformer  (B=2, T=2048, D=1024, E=2048, S=128, L=4, V=32000)
// Round 2: 256x256 8-phase counted-vmcnt GEMM (T2+T3+T4+T5) for head + u/v;
//          128x128 m97-style GEMM for qk/scores/av/Wo; av epilogue fuses gate.
// ---------------------------------------------------------------------------

#define Bz 2
#define Tt 2048
#define Dd 1024
#define Ee 2048
#define Ss 128
#define Ll 4
#define Vv 32000
#define BT (Bz * Tt)   // 4096

typedef __attribute__((ext_vector_type(8))) _Float16 f16x8;
typedef __attribute__((ext_vector_type(4))) _Float16 f16x4;
typedef __attribute__((ext_vector_type(4))) float    f32x4;

__device__ __forceinline__ void load_lds16(const void* g, void* l) {
  __builtin_amdgcn_global_load_lds(
      (const __attribute__((address_space(1))) void*)g,
      (__attribute__((address_space(3))) void*)l, 16, 0, 0);
}

#define FENCE asm volatile("" ::: "memory")
#define BARRIER do { FENCE; __builtin_amdgcn_s_barrier(); FENCE; } while (0)
#define LGKM0 do { asm volatile("s_waitcnt lgkmcnt(0)" ::: "memory"); \
                   __builtin_amdgcn_sched_barrier(0); } while (0)

enum { EPI_F32 = 0, EPI_SILU = 1, EPI_SCORES = 2, EPI_RESID = 3, EPI_GATED = 4 };

// bijective XCD swizzle (m204)
__device__ __forceinline__ int xcd_swz(int id, int nwg) {
  int q = nwg >> 3, r = nwg & 7;
  int x = id & 7, o = id >> 3;
  return (x < r ? x * (q + 1) : r * (q + 1) + (x - r) * q) + o;
}

// ===========================================================================
// 256x256 tile, BK=64, 8 waves (2M x 4N), 4 phases/K-tile, counted vmcnt,
// granule-XOR LDS swizzle (write via pre-swizzled global src, read swizzled).
// Requires M%256==0, N%256==0, K%64==0, K>=128.
// ===========================================================================
template <int EPI>
__global__ void __launch_bounds__(512) gemm256(
    const _Float16* __restrict__ A, long sA,
    const _Float16* __restrict__ Bt, long sB,
    void* __restrict__ Cp, long sC,
    int M, int N, int K, int lda, int ldb, int ldc) {
  const int bz = blockIdx.z;
  A += (size_t)bz * sA;
  Bt += (size_t)bz * sB;

  const int nbm = M >> 8;
  const int id = xcd_swz(blockIdx.x, gridDim.x);
  const int bm = id % nbm, bn = id / nbm;
  const int row0 = bm << 8, col0 = bn << 8;

  __shared__ __align__(16) _Float16 Abuf[2][256 * 64];
  __shared__ __align__(16) _Float16 Bbuf[2][256 * 64];

  const int tid = threadIdx.x, lane = tid & 63, w = tid >> 6;
  const int mu = w >> 2, nu = w & 3;     // wave grid 2(M) x 4(N)
  const int fr = lane & 15, kg = lane >> 4;
  // staging: each load instr = one 64-row x 64-col quarter (8 KB)
  const int srow = (w << 3) + (lane >> 3);           // row in quarter
  const int sg = (lane & 7) ^ ((lane >> 3) & 7);     // pre-swizzled src granule
  const _Float16* Asrc = A + (size_t)(row0 + srow) * lda + sg * 8;
  const _Float16* Bsrc = Bt + (size_t)(col0 + srow) * ldb + sg * 8;
  // swizzled read granule offsets (elements), ks = 0,1
  const int gx[2] = { ((kg) ^ (fr & 7)) << 3, ((4 + kg) ^ (fr & 7)) << 3 };

#define ST_A(BUF, KT, Q) load_lds16(Asrc + (size_t)(Q) * 64 * lda + (size_t)(KT) * 64, \
                                    (void*)&Abuf[BUF][(Q) * 4096 + (w << 9)])
#define ST_B(BUF, KT, Q) load_lds16(Bsrc + (size_t)(Q) * 64 * ldb + (size_t)(KT) * 64, \
                                    (void*)&Bbuf[BUF][(Q) * 4096 + (w << 9)])
#define RD_A(BUF, MH)                                                          \
  { _Pragma("unroll") for (int j = 0; j < 4; ++j)                              \
    _Pragma("unroll") for (int ks = 0; ks < 2; ++ks)                           \
      af[j][ks] = *(const f16x8*)&Abuf[BUF][(mu * 128 + (MH) * 64 + j * 16 + fr) * 64 + gx[ks]]; }
#define RD_B(BUF, NH, BQ)                                                      \
  { _Pragma("unroll") for (int i = 0; i < 2; ++i)                              \
    _Pragma("unroll") for (int ks = 0; ks < 2; ++ks)                           \
      BQ[i][ks] = *(const f16x8*)&Bbuf[BUF][(nu * 64 + (NH) * 32 + i * 16 + fr) * 64 + gx[ks]]; }
#define MFMA_Q(MH, NH, BQ)                                                     \
  { _Pragma("unroll") for (int j = 0; j < 4; ++j)                              \
    _Pragma("unroll") for (int i = 0; i < 2; ++i)                              \
    _Pragma("unroll") for (int ks = 0; ks < 2; ++ks)                           \
      acc[(MH) * 4 + j][(NH) * 2 + i] = __builtin_amdgcn_mfma_f32_16x16x32_f16( \
          af[j][ks], BQ[i][ks], acc[(MH) * 4 + j][(NH) * 2 + i], 0, 0, 0); }

  f32x4 acc[8][4];
#pragma unroll
  for (int m = 0; m < 8; ++m)
#pragma unroll
    for (int n = 0; n < 4; ++n)
#pragma unroll
      for (int e = 0; e < 4; ++e) acc[m][n][e] = 0.f;

  f16x8 af[4][2], bfA[2][2], bfB[2][2];

  const int NT = K >> 6;
  // prologue: stage tile 0 -> buf0 ; issue order B0,B1,B2,B3,A0,A2,A1,A3
  ST_B(0, 0, 0); ST_B(0, 0, 1); ST_B(0, 0, 2); ST_B(0, 0, 3);
  ST_A(0, 0, 0); ST_A(0, 0, 2); ST_A(0, 0, 1); ST_A(0, 0, 3);
  asm volatile("s_waitcnt vmcnt(2)" ::: "memory");  // idx<=5 resident
  BARRIER;

  for (int t = 0; t < NT; ++t) {
    const int b = t & 1, nb = b ^ 1;
    const int kn = (t + 1 < NT) ? t + 1 : t;  // tail: re-stage (never read)
    // ---- P0: quadrant (mh0, nh0)
    RD_A(b, 0);
    RD_B(b, 0, bfA);
    ST_B(nb, kn, 0); ST_B(nb, kn, 1);
    BARRIER;
    LGKM0;
    __builtin_amdgcn_s_setprio(1); MFMA_Q(0, 0, bfA); __builtin_amdgcn_s_setprio(0);
    BARRIER;
    // ---- P1: (mh0, nh1)
    RD_B(b, 1, bfB);
    ST_B(nb, kn, 2); ST_B(nb, kn, 3);
    BARRIER;
    LGKM0;
    __builtin_amdgcn_s_setprio(1); MFMA_Q(0, 1, bfB); __builtin_amdgcn_s_setprio(0);
    asm volatile("s_waitcnt vmcnt(4)" ::: "memory");  // tile t A-odd quarters in
    BARRIER;
    // ---- P2: (mh1, nh0)
    RD_A(b, 1);
    ST_A(nb, kn, 0); ST_A(nb, kn, 2);
    BARRIER;
    LGKM0;
    __builtin_amdgcn_s_setprio(1); MFMA_Q(1, 0, bfA); __builtin_amdgcn_s_setprio(0);
    BARRIER;
    // ---- P3: (mh1, nh1)
    ST_A(nb, kn, 1); ST_A(nb, kn, 3);
    BARRIER;
    LGKM0;
    __builtin_amdgcn_s_setprio(1); MFMA_Q(1, 1, bfB); __builtin_amdgcn_s_setprio(0);
    asm volatile("s_waitcnt vmcnt(2)" ::: "memory");  // tile t+1 idx<=5 resident
    BARRIER;
  }
  asm volatile("s_waitcnt vmcnt(0)" ::: "memory");

  // epilogue: C/D layout col=lane&15, row=(lane>>4)*4+reg
#pragma unroll
  for (int m = 0; m < 8; ++m) {
    int gr0 = row0 + mu * 128 + m * 16 + (kg << 2);
#pragma unroll
    for (int n = 0; n < 4; ++n) {
      int gc = col0 + nu * 64 + n * 16 + fr;
#pragma unroll
      for (int r = 0; r < 4; ++r) {
        float v = acc[m][n][r];
        size_t ci = (size_t)(gr0 + r) * ldc + gc;
        if (EPI == EPI_F32) {
          ((float*)Cp + (size_t)bz * sC)[ci] = v;
        } else {  // EPI_SILU
          ((_Float16*)Cp + (size_t)bz * sC)[ci] = (_Float16)(v / (1.f + expf(-v)));
        }
      }
    }
  }
#undef ST_A
#undef ST_B
#undef RD_A
#undef RD_B
#undef MFMA_Q
}

// ===========================================================================
// 128x128 m97-style GEMM (validated R1) for qk / scores / av / Wo.
// ===========================================================================
#define BM 128
#define BN 128
#define BK 32

template <int EPI>
__global__ void __launch_bounds__(256, 2) gemm_bt(
    const _Float16* __restrict__ A, long sA,
    const _Float16* __restrict__ Bt, long sB,
    void* __restrict__ Cp, long sC,
    int M, int N, int K, int lda, int ldb, int ldc, int causal,
    const _Float16* __restrict__ U) {
  int bm = blockIdx.x, bn = blockIdx.y, bz = blockIdx.z;
  if (EPI == EPI_SCORES && bn > bm) return;
  A += (size_t)bz * sA;
  Bt += (size_t)bz * sB;

  int Keff = K;
  if (causal == 2) {
    int km = (bm + 1) * BM;
    Keff = km < K ? km : K;
  }

  __shared__ __align__(16) _Float16 As[BM * BK];
  __shared__ __align__(16) _Float16 Bs[BN * BK];

  int tid = threadIdx.x;
  int lane = tid & 63, wave = tid >> 6;
  int wr = (wave >> 1) << 6;
  int wc = (wave & 1) << 6;
  int row0 = bm * BM, col0 = bn * BN;
  int fr = lane & 15;
  int kg = lane >> 4;
  int srow = lane >> 2;
  int scol = (lane & 3) << 3;

  f32x4 acc[4][4];
#pragma unroll
  for (int i = 0; i < 4; i++)
#pragma unroll
    for (int j = 0; j < 4; j++)
#pragma unroll
      for (int e = 0; e < 4; e++) acc[i][j][e] = 0.f;

  const f16x8* As8 = (const f16x8*)As;
  const f16x8* Bs8 = (const f16x8*)Bs;

  for (int k0 = 0; k0 < Keff; k0 += BK) {
    __syncthreads();
#pragma unroll
    for (int i = 0; i < 2; i++) {
      int rb = (wave * 2 + i) * 16;
      load_lds16(A + (size_t)(row0 + rb + srow) * lda + k0 + scol,
                 (void*)&As[rb * BK]);
      load_lds16(Bt + (size_t)(col0 + rb + srow) * ldb + k0 + scol,
                 (void*)&Bs[rb * BK]);
    }
    asm volatile("s_waitcnt vmcnt(0)" ::: "memory");
    __syncthreads();

    f16x8 af[4], bf[4];
#pragma unroll
    for (int m = 0; m < 4; m++)
      af[m] = As8[(size_t)(wr + m * 16 + fr) * (BK / 8) + kg];
#pragma unroll
    for (int n = 0; n < 4; n++)
      bf[n] = Bs8[(size_t)(wc + n * 16 + fr) * (BK / 8) + kg];
#pragma unroll
    for (int m = 0; m < 4; m++)
#pragma unroll
      for (int n = 0; n < 4; n++)
        acc[m][n] =
            __builtin_amdgcn_mfma_f32_16x16x32_f16(af[m], bf[n], acc[m][n], 0, 0, 0);
  }

#pragma unroll
  for (int m = 0; m < 4; m++) {
    int gr0 = row0 + wr + m * 16 + (kg << 2);
#pragma unroll
    for (int n = 0; n < 4; n++) {
      int gc = col0 + wc + n * 16 + fr;
#pragma unroll
      for (int r = 0; r < 4; r++) {
        float v = acc[m][n][r];
        size_t ci = (size_t)(gr0 + r) * ldc + gc;
        if (EPI == EPI_F32) {
          ((float*)Cp + (size_t)bz * sC)[ci] = v;
        } else if (EPI == EPI_SILU) {
          ((_Float16*)Cp + (size_t)bz * sC)[ci] =
              (_Float16)(v / (1.f + expf(-v)));
        } else if (EPI == EPI_SCORES) {
          float s = v * 0.08838834764831845f;  // 1/sqrt(128)
          s = fmaxf(s, 0.f);
          s = (gc <= gr0 + r) ? s * s : 0.f;
          ((_Float16*)Cp + (size_t)bz * sC)[ci] = (_Float16)s;
        } else if (EPI == EPI_GATED) {  // gh = u * (attn@v)
          const _Float16* Ub = U + (size_t)bz * sC;
          ((_Float16*)Cp + (size_t)bz * sC)[ci] = (_Float16)((float)Ub[ci] * v);
        } else {  // EPI_RESID
          ((float*)Cp)[ci] += v;
        }
      }
    }
  }
}

__global__ void __launch_bounds__(256) ln_kernel(const float* __restrict__ x,
                                                 const float* __restrict__ g,
                                                 const float* __restrict__ b,
                                                 _Float16* __restrict__ out) {
  int row = blockIdx.x, tid = threadIdx.x;
  float4 v = ((const float4*)(x + (size_t)row * Dd))[tid];
  float s = v.x + v.y + v.z + v.w;
  float q = v.x * v.x + v.y * v.y + v.z * v.z + v.w * v.w;
#pragma unroll
  for (int off = 32; off > 0; off >>= 1) {
    s += __shfl_down(s, off, 64);
    q += __shfl_down(q, off, 64);
  }
  __shared__ float ss[4], sq[4];
  int lane = tid & 63, wv = tid >> 6;
  if (lane == 0) { ss[wv] = s; sq[wv] = q; }
  __syncthreads();
  s = ss[0] + ss[1] + ss[2] + ss[3];
  q = sq[0] + sq[1] + sq[2] + sq[3];
  float mu = s * (1.f / Dd);
  float var = q * (1.f / Dd) - mu * mu;
  float rs = rsqrtf(var + 1e-5f);
  float4 gg = ((const float4*)g)[tid];
  float4 bb = ((const float4*)b)[tid];
  f16x4 o;
  o[0] = (_Float16)((v.x - mu) * rs * gg.x + bb.x);
  o[1] = (_Float16)((v.y - mu) * rs * gg.y + bb.y);
  o[2] = (_Float16)((v.z - mu) * rs * gg.z + bb.z);
  o[3] = (_Float16)((v.w - mu) * rs * gg.w + bb.w);
  ((f16x4*)(out + (size_t)row * Dd))[tid] = o;
}

__global__ void embed_kernel(const int* __restrict__ toks,
                             const float* __restrict__ emb,
                             float* __restrict__ x) {
  int row = blockIdx.x, tid = threadIdx.x;
  long t = toks[row];
  ((float4*)(x + (size_t)row * Dd))[tid] =
      ((const float4*)(emb + (size_t)t * Dd))[tid];
}

__global__ void rope_table_kernel(float* __restrict__ cosT,
                                  float* __restrict__ sinT) {
  int idx = blockIdx.x * 256 + threadIdx.x;  // T*64
  int t = idx >> 6, i = idx & 63;
  float inv = powf(10000.f, (float)(2 * i) * (-1.f / 128.f));
  float a = (float)t * inv;
  cosT[idx] = cosf(a);
  sinT[idx] = sinf(a);
}

__global__ void rope_kernel(const float* __restrict__ pre,
                            _Float16* __restrict__ o16,
                            const float* __restrict__ cosT,
                            const float* __restrict__ sinT) {
  int row = blockIdx.x * 4 + threadIdx.y;
  int i = threadIdx.x;
  int z = blockIdx.y;
  const float* p = pre + (size_t)z * BT * Ss + (size_t)row * Ss;
  _Float16* o = o16 + (size_t)z * BT * Ss + (size_t)row * Ss;
  int t = row & (Tt - 1);
  float c = cosT[t * 64 + i], sn = sinT[t * 64 + i];
  float x1 = p[i], x2 = p[i + 64];
  o[i] = (_Float16)(x1 * c - x2 * sn);
  o[i + 64] = (_Float16)(x1 * sn + x2 * c);
}

// out(C x R) = transpose(in(R x C)), convert to f16.
template <typename TIn>
__global__ void transconv_kernel(const TIn* __restrict__ in,
                                 _Float16* __restrict__ out, int R, int C,
                                 long s_in, long s_out) {
  __shared__ float tile[64][65];
  in += (size_t)blockIdx.z * s_in;
  out += (size_t)blockIdx.z * s_out;
  int r0 = blockIdx.y * 64, c0 = blockIdx.x * 64;
  int tx = threadIdx.x & 63, ty = threadIdx.x >> 6;
#pragma unroll
  for (int p = 0; p < 16; p++) {
    int r = p * 4 + ty;
    tile[r][tx] = (float)in[(size_t)(r0 + r) * C + c0 + tx];
  }
  __syncthreads();
#pragma unroll
  for (int p = 0; p < 16; p++) {
    int r = p * 4 + ty;
    out[(size_t)(c0 + r) * R + r0 + tx] = (_Float16)tile[tx][r];
  }
}

extern "C" void kernel_launch(void* const* d_in, const int* in_sizes, int n_in,
                              void* d_out, int out_size, void* d_ws,
                              size_t ws_size, hipStream_t stream) {
  const int*   tokens = (const int*)d_in[0];
  const float* emb    = (const float*)d_in[1];
  const float* Wu     = (const float*)d_in[2];
  const float* Wv     = (const float*)d_in[3];
  const float* Wq     = (const float*)d_in[4];
  const float* Wk     = (const float*)d_in[5];
  const float* Wo     = (const float*)d_in[6];
  const float* ln_g   = (const float*)d_in[7];
  const float* ln_b   = (const float*)d_in[8];
  const float* lnf_g  = (const float*)d_in[9];
  const float* lnf_b  = (const float*)d_in[10];
  const float* Wlm    = (const float*)d_in[11];
  float* out = (float*)d_out;
  (void)in_sizes; (void)n_in; (void)out_size;

  char* wsp = (char*)d_ws;
  size_t off = 0;
  auto alloc = [&](size_t bytes) -> void* {
    void* p = wsp + off;
    off = (off + bytes + 255) & ~(size_t)255;
    return p;
  };

  float*    x     = (float*)alloc((size_t)BT * Dd * 4);
  _Float16* xn    = (_Float16*)alloc((size_t)BT * Dd * 2);
  _Float16* uvh   = (_Float16*)alloc((size_t)2 * BT * Ee * 2);
  _Float16* vT    = (_Float16*)alloc((size_t)Bz * Ee * Tt * 2);
  float*    qkpre = (float*)alloc((size_t)2 * BT * Ss * 4);
  _Float16* qkh   = (_Float16*)alloc((size_t)2 * BT * Ss * 2);
  _Float16* attn  = (_Float16*)alloc((size_t)Bz * Tt * Tt * 2);
  _Float16* gh    = (_Float16*)alloc((size_t)BT * Ee * 2);
  float*    cosT  = (float*)alloc((size_t)Tt * 64 * 4);
  float*    sinT  = (float*)alloc((size_t)Tt * 64 * 4);
  _Float16* WuvT  = (_Float16*)alloc((size_t)2 * Ll * Ee * Dd * 2);
  _Float16* WqkT  = (_Float16*)alloc((size_t)2 * Ll * Ss * Ee * 2);
  _Float16* WoT   = (_Float16*)alloc((size_t)Ll * Dd * Ee * 2);
  _Float16* WlmT  = (_Float16*)alloc((size_t)Vv * Dd * 2);
  if (off > ws_size) return;

  transconv_kernel<float><<<dim3(Ee / 64, Dd / 64, Ll), 256, 0, stream>>>(
      Wu, WuvT, Dd, Ee, (long)Dd * Ee, (long)Ee * Dd);
  transconv_kernel<float><<<dim3(Ee / 64, Dd / 64, Ll), 256, 0, stream>>>(
      Wv, WuvT + (size_t)Ll * Ee * Dd, Dd, Ee, (long)Dd * Ee, (long)Ee * Dd);
  transconv_kernel<float><<<dim3(Ss / 64, Ee / 64, Ll), 256, 0, stream>>>(
      Wq, WqkT, Ee, Ss, (long)Ee * Ss, (long)Ss * Ee);
  transconv_kernel<float><<<dim3(Ss / 64, Ee / 64, Ll), 256, 0, stream>>>(
      Wk, WqkT + (size_t)Ll * Ss * Ee, Ee, Ss, (long)Ee * Ss, (long)Ss * Ee);
  transconv_kernel<float><<<dim3(Dd / 64, Ee / 64, Ll), 256, 0, stream>>>(
      Wo, WoT, Ee, Dd, (long)Ee * Dd, (long)Dd * Ee);
  transconv_kernel<float><<<dim3(Vv / 64, Dd / 64, 1), 256, 0, stream>>>(
      Wlm, WlmT, Dd, Vv, 0, 0);

  rope_table_kernel<<<(Tt * 64) / 256, 256, 0, stream>>>(cosT, sinT);
  embed_kernel<<<BT, 256, 0, stream>>>(tokens, emb, x);

  for (int l = 0; l < Ll; l++) {
    ln_kernel<<<BT, 256, 0, stream>>>(x, ln_g + (size_t)l * Dd,
                                      ln_b + (size_t)l * Dd, xn);
    // u = silu(xn@Wu), v = silu(xn@Wv)  -- 256^2 8-phase kernel
    gemm256<EPI_SILU><<<dim3((BT / 256) * (Ee / 256), 1, 2), 512, 0, stream>>>(
        xn, 0, WuvT + (size_t)l * Ee * Dd, (long)Ll * Ee * Dd, (void*)uvh,
        (long)BT * Ee, BT, Ee, Dd, Dd, Dd, Ee);
    // q_pre = u@Wq, k_pre = v@Wk
    gemm_bt<EPI_F32><<<dim3(BT / BM, Ss / BN, 2), 256, 0, stream>>>(
        uvh, (long)BT * Ee, WqkT + (size_t)l * Ss * Ee, (long)Ll * Ss * Ee,
        (void*)qkpre, (long)BT * Ss, BT, Ss, Ee, Ee, Ee, Ss, 0, nullptr);
    rope_kernel<<<dim3(BT / 4, 2), dim3(64, 4), 0, stream>>>(qkpre, qkh, cosT,
                                                             sinT);
    transconv_kernel<_Float16><<<dim3(Ee / 64, Tt / 64, Bz), 256, 0, stream>>>(
        uvh + (size_t)BT * Ee, vT, Tt, Ee, (long)Tt * Ee, (long)Ee * Tt);
    // scores = relu(mask(q@k^T * scale))^2
    gemm_bt<EPI_SCORES><<<dim3(Tt / BM, Tt / BN, Bz), 256, 0, stream>>>(
        qkh, (long)Tt * Ss, qkh + (size_t)BT * Ss, (long)Tt * Ss, (void*)attn,
        (long)Tt * Tt, Tt, Tt, Ss, Ss, Ss, Tt, 0, nullptr);
    // gh = u * (attn @ v)   (gate fused into av epilogue)
    gemm_bt<EPI_GATED><<<dim3(Tt / BM, Ee / BN, Bz), 256, 0, stream>>>(
        attn, (long)Tt * Tt, vT, (long)Ee * Tt, (void*)gh, (long)Tt * Ee, Tt,
        Ee, Tt, Tt, Tt, Ee, 2, uvh);
    // x += gh @ Wo
    gemm_bt<EPI_RESID><<<dim3(BT / BM, Dd / BN, 1), 256, 0, stream>>>(
        gh, 0, WoT + (size_t)l * Dd * Ee, 0, (void*)x, 0, BT, Dd, Ee, Ee, Ee,
        Dd, 0, nullptr);
  }

  ln_kernel<<<BT, 256, 0, stream>>>(x, lnf_g, lnf_b, xn);
  // logits = xn @ Wlm   -- 256^2 8-phase kernel
  gemm256<EPI_F32><<<dim3((BT / 256) * (Vv / 256), 1, 1), 512, 0, stream>>>(
      xn, 0, WlmT, 0, (void*)out, 0, BT, Vv, Dd, Dd, Dd, Vv);
}

// Round 4
// 1327.674 us; speedup vs baseline: 1.0770x; 1.0464x over previous
//
#include <hip/hip_runtime.h>
#include <math.h>

// ---------------------------------------------------------------------------
// GatedAttentionTransformer  (B=2, T=2048, D=1024, E=2048, S=128, L=4, V=32000)
// Round 4: R3 epilogue (LDS-bounce + coalesced full-row stores) with the
//          missing `col0` in both global store paths fixed.
// ---------------------------------------------------------------------------

#define Bz 2
#define Tt 2048
#define Dd 1024
#define Ee 2048
#define Ss 128
#define Ll 4
#define Vv 32000
#define BT (Bz * Tt)   // 4096

typedef __attribute__((ext_vector_type(8))) _Float16 f16x8;
typedef __attribute__((ext_vector_type(4))) _Float16 f16x4;
typedef __attribute__((ext_vector_type(4))) float    f32x4;

__device__ __forceinline__ void load_lds16(const void* g, void* l) {
  __builtin_amdgcn_global_load_lds(
      (const __attribute__((address_space(1))) void*)g,
      (__attribute__((address_space(3))) void*)l, 16, 0, 0);
}

#define FENCE asm volatile("" ::: "memory")
#define BARRIER do { FENCE; __builtin_amdgcn_s_barrier(); FENCE; } while (0)
#define LGKM0 do { asm volatile("s_waitcnt lgkmcnt(0)" ::: "memory"); \
                   __builtin_amdgcn_sched_barrier(0); } while (0)

enum { EPI_F32 = 0, EPI_SILU = 1, EPI_SCORES = 2, EPI_RESID = 3, EPI_GATED = 4 };

// bijective XCD swizzle (m204)
__device__ __forceinline__ int xcd_swz(int id, int nwg) {
  int q = nwg >> 3, r = nwg & 7;
  int x = id & 7, o = id >> 3;
  return (x < r ? x * (q + 1) : r * (q + 1) + (x - r) * q) + o;
}

// ===========================================================================
// 256x256 tile, BK=64, 8 waves (2M x 4N), 4 phases/K-tile, counted vmcnt,
// granule-XOR LDS swizzle. Epilogue: LDS-bounce -> coalesced dwordx4 rows.
// Requires M%256==0, N%256==0, K%64==0, K>=128.
// ===========================================================================
template <int EPI>
__global__ void __launch_bounds__(512) gemm256(
    const _Float16* __restrict__ A, long sA,
    const _Float16* __restrict__ Bt, long sB,
    void* __restrict__ Cp, long sC,
    int M, int N, int K, int lda, int ldb, int ldc) {
  const int bz = blockIdx.z;
  A += (size_t)bz * sA;
  Bt += (size_t)bz * sB;

  const int nbm = M >> 8;
  const int id = xcd_swz(blockIdx.x, gridDim.x);
  const int bm = id % nbm, bn = id / nbm;
  const int row0 = bm << 8, col0 = bn << 8;

  // 128 KiB shared: K-loop = A dbuf (64K) | B dbuf (64K); epilogue = bounce
  __shared__ __align__(16) char smem[131072];
  _Float16* const Abuf0 = (_Float16*)smem;             // [2][16384]
  _Float16* const Bbuf0 = (_Float16*)(smem + 65536);   // [2][16384]

  const int tid = threadIdx.x, lane = tid & 63, w = tid >> 6;
  const int mu = w >> 2, nu = w & 3;     // wave grid 2(M) x 4(N)
  const int fr = lane & 15, kg = lane >> 4;
  // staging: each load instr = one 64-row x 64-col quarter (8 KB)
  const int srow = (w << 3) + (lane >> 3);           // row in quarter
  const int sg = (lane & 7) ^ ((lane >> 3) & 7);     // pre-swizzled src granule
  const _Float16* Asrc = A + (size_t)(row0 + srow) * lda + sg * 8;
  const _Float16* Bsrc = Bt + (size_t)(col0 + srow) * ldb + sg * 8;
  // swizzled read granule offsets (elements), ks = 0,1
  const int gx[2] = { ((kg) ^ (fr & 7)) << 3, ((4 + kg) ^ (fr & 7)) << 3 };

#define ST_A(BUF, KT, Q) load_lds16(Asrc + (size_t)(Q) * 64 * lda + (size_t)(KT) * 64, \
                                    (void*)&Abuf0[(BUF) * 16384 + (Q) * 4096 + (w << 9)])
#define ST_B(BUF, KT, Q) load_lds16(Bsrc + (size_t)(Q) * 64 * ldb + (size_t)(KT) * 64, \
                                    (void*)&Bbuf0[(BUF) * 16384 + (Q) * 4096 + (w << 9)])
#define RD_A(BUF, MH)                                                          \
  { _Pragma("unroll") for (int j = 0; j < 4; ++j)                              \
    _Pragma("unroll") for (int ks = 0; ks < 2; ++ks)                           \
      af[j][ks] = *(const f16x8*)&Abuf0[(BUF) * 16384 +                        \
          (mu * 128 + (MH) * 64 + j * 16 + fr) * 64 + gx[ks]]; }
#define RD_B(BUF, NH, BQ)                                                      \
  { _Pragma("unroll") for (int i = 0; i < 2; ++i)                              \
    _Pragma("unroll") for (int ks = 0; ks < 2; ++ks)                           \
      BQ[i][ks] = *(const f16x8*)&Bbuf0[(BUF) * 16384 +                        \
          (nu * 64 + (NH) * 32 + i * 16 + fr) * 64 + gx[ks]]; }
#define MFMA_Q(MH, NH, BQ)                                                     \
  { _Pragma("unroll") for (int j = 0; j < 4; ++j)                              \
    _Pragma("unroll") for (int i = 0; i < 2; ++i)                              \
    _Pragma("unroll") for (int ks = 0; ks < 2; ++ks)                           \
      acc[(MH) * 4 + j][(NH) * 2 + i] = __builtin_amdgcn_mfma_f32_16x16x32_f16( \
          af[j][ks], BQ[i][ks], acc[(MH) * 4 + j][(NH) * 2 + i], 0, 0, 0); }

  f32x4 acc[8][4];
#pragma unroll
  for (int m = 0; m < 8; ++m)
#pragma unroll
    for (int n = 0; n < 4; ++n)
#pragma unroll
      for (int e = 0; e < 4; ++e) acc[m][n][e] = 0.f;

  f16x8 af[4][2], bfA[2][2], bfB[2][2];

  const int NT = K >> 6;
  // prologue: stage tile 0 -> buf0
  ST_B(0, 0, 0); ST_B(0, 0, 1); ST_B(0, 0, 2); ST_B(0, 0, 3);
  ST_A(0, 0, 0); ST_A(0, 0, 2); ST_A(0, 0, 1); ST_A(0, 0, 3);
  asm volatile("s_waitcnt vmcnt(2)" ::: "memory");
  BARRIER;

  for (int t = 0; t < NT; ++t) {
    const int b = t & 1, nb = b ^ 1;
    const int kn = (t + 1 < NT) ? t + 1 : t;  // tail: re-stage (never read)
    // ---- P0: quadrant (mh0, nh0)
    RD_A(b, 0);
    RD_B(b, 0, bfA);
    ST_B(nb, kn, 0); ST_B(nb, kn, 1);
    BARRIER;
    LGKM0;
    __builtin_amdgcn_s_setprio(1); MFMA_Q(0, 0, bfA); __builtin_amdgcn_s_setprio(0);
    BARRIER;
    // ---- P1: (mh0, nh1)
    RD_B(b, 1, bfB);
    ST_B(nb, kn, 2); ST_B(nb, kn, 3);
    BARRIER;
    LGKM0;
    __builtin_amdgcn_s_setprio(1); MFMA_Q(0, 1, bfB); __builtin_amdgcn_s_setprio(0);
    asm volatile("s_waitcnt vmcnt(4)" ::: "memory");
    BARRIER;
    // ---- P2: (mh1, nh0)
    RD_A(b, 1);
    ST_A(nb, kn, 0); ST_A(nb, kn, 2);
    BARRIER;
    LGKM0;
    __builtin_amdgcn_s_setprio(1); MFMA_Q(1, 0, bfA); __builtin_amdgcn_s_setprio(0);
    BARRIER;
    // ---- P3: (mh1, nh1)
    ST_A(nb, kn, 1); ST_A(nb, kn, 3);
    BARRIER;
    LGKM0;
    __builtin_amdgcn_s_setprio(1); MFMA_Q(1, 1, bfB); __builtin_amdgcn_s_setprio(0);
    asm volatile("s_waitcnt vmcnt(2)" ::: "memory");
    BARRIER;
  }
  asm volatile("s_waitcnt vmcnt(0)" ::: "memory");

  // ---- epilogue: LDS bounce -> coalesced full-row stores --------------------
  // acc fragment (m,n,r): row_local(in mu-half) = m*16 + kg*4 + r,
  //                       col = nu*64 + n*16 + fr.
  // 16B-granule XOR swizzle keyed on (row&7): write <=2-way, read conflict-free.
  if (EPI == EPI_F32) {
    float* Cb = (float*)Cp + (size_t)bz * sC;
#pragma unroll
    for (int p = 0; p < 2; ++p) {   // pass p: tile rows [p*128, p*128+128)
      __syncthreads();              // prior pass reads / K-loop done
      if (mu == p) {
#pragma unroll
        for (int m = 0; m < 8; ++m)
#pragma unroll
          for (int n = 0; n < 4; ++n) {
            int rl = m * 16 + (kg << 2);
            int col = nu * 64 + n * 16 + fr;
#pragma unroll
            for (int r = 0; r < 4; ++r) {
              int row = rl + r;
              *(float*)(smem + (row << 10) + ((col << 2) ^ ((row & 7) << 4))) =
                  acc[m][n][r];
            }
          }
      }
      __syncthreads();
#pragma unroll
      for (int j = 0; j < 16; ++j) {
        int row = j * 8 + w;        // 8 rows per round (one per wave)
        f32x4 d = *(const f32x4*)(smem + (row << 10) +
                                  ((lane << 4) ^ ((row & 7) << 4)));
        *(f32x4*)&Cb[(size_t)(row0 + p * 128 + row) * ldc + col0 + (lane << 2)] = d;
      }
    }
  } else {  // EPI_SILU: f16 output, 256x256x2B = 128K, single pass
    _Float16* Ch = (_Float16*)Cp + (size_t)bz * sC;
    __syncthreads();
#pragma unroll
    for (int m = 0; m < 8; ++m)
#pragma unroll
      for (int n = 0; n < 4; ++n) {
        int rl = mu * 128 + m * 16 + (kg << 2);
        int col = nu * 64 + n * 16 + fr;
#pragma unroll
        for (int r = 0; r < 4; ++r) {
          int row = rl + r;
          float v = acc[m][n][r];
          *(_Float16*)(smem + (row << 9) + ((col << 1) ^ ((row & 7) << 4))) =
              (_Float16)(v / (1.f + expf(-v)));
        }
      }
    __syncthreads();
#pragma unroll
    for (int j = 0; j < 16; ++j) {
      int row = j * 16 + w * 2 + (lane >> 5);  // 16 rows per round
      int g = lane & 31;
      f16x8 d = *(const f16x8*)(smem + (row << 9) +
                                ((g << 4) ^ ((row & 7) << 4)));
      *(f16x8*)&Ch[(size_t)(row0 + row) * ldc + col0 + (g << 3)] = d;
    }
  }
#undef ST_A
#undef ST_B
#undef RD_A
#undef RD_B
#undef MFMA_Q
}

// ===========================================================================
// 128x128 m97-style GEMM (validated R1) for qk / scores / av / Wo.
// ===========================================================================
#define BM 128
#define BN 128
#define BK 32

template <int EPI>
__global__ void __launch_bounds__(256, 2) gemm_bt(
    const _Float16* __restrict__ A, long sA,
    const _Float16* __restrict__ Bt, long sB,
    void* __restrict__ Cp, long sC,
    int M, int N, int K, int lda, int ldb, int ldc, int causal,
    const _Float16* __restrict__ U) {
  int bm = blockIdx.x, bn = blockIdx.y, bz = blockIdx.z;
  if (EPI == EPI_SCORES && bn > bm) return;
  A += (size_t)bz * sA;
  Bt += (size_t)bz * sB;

  int Keff = K;
  if (causal == 2) {
    int km = (bm + 1) * BM;
    Keff = km < K ? km : K;
  }

  __shared__ __align__(16) _Float16 As[BM * BK];
  __shared__ __align__(16) _Float16 Bs[BN * BK];

  int tid = threadIdx.x;
  int lane = tid & 63, wave = tid >> 6;
  int wr = (wave >> 1) << 6;
  int wc = (wave & 1) << 6;
  int row0 = bm * BM, col0 = bn * BN;
  int fr = lane & 15;
  int kg = lane >> 4;
  int srow = lane >> 2;
  int scol = (lane & 3) << 3;

  f32x4 acc[4][4];
#pragma unroll
  for (int i = 0; i < 4; i++)
#pragma unroll
    for (int j = 0; j < 4; j++)
#pragma unroll
      for (int e = 0; e < 4; e++) acc[i][j][e] = 0.f;

  const f16x8* As8 = (const f16x8*)As;
  const f16x8* Bs8 = (const f16x8*)Bs;

  for (int k0 = 0; k0 < Keff; k0 += BK) {
    __syncthreads();
#pragma unroll
    for (int i = 0; i < 2; i++) {
      int rb = (wave * 2 + i) * 16;
      load_lds16(A + (size_t)(row0 + rb + srow) * lda + k0 + scol,
                 (void*)&As[rb * BK]);
      load_lds16(Bt + (size_t)(col0 + rb + srow) * ldb + k0 + scol,
                 (void*)&Bs[rb * BK]);
    }
    asm volatile("s_waitcnt vmcnt(0)" ::: "memory");
    __syncthreads();

    f16x8 af[4], bf[4];
#pragma unroll
    for (int m = 0; m < 4; m++)
      af[m] = As8[(size_t)(wr + m * 16 + fr) * (BK / 8) + kg];
#pragma unroll
    for (int n = 0; n < 4; n++)
      bf[n] = Bs8[(size_t)(wc + n * 16 + fr) * (BK / 8) + kg];
#pragma unroll
    for (int m = 0; m < 4; m++)
#pragma unroll
      for (int n = 0; n < 4; n++)
        acc[m][n] =
            __builtin_amdgcn_mfma_f32_16x16x32_f16(af[m], bf[n], acc[m][n], 0, 0, 0);
  }

#pragma unroll
  for (int m = 0; m < 4; m++) {
    int gr0 = row0 + wr + m * 16 + (kg << 2);
#pragma unroll
    for (int n = 0; n < 4; n++) {
      int gc = col0 + wc + n * 16 + fr;
#pragma unroll
      for (int r = 0; r < 4; r++) {
        float v = acc[m][n][r];
        size_t ci = (size_t)(gr0 + r) * ldc + gc;
        if (EPI == EPI_F32) {
          ((float*)Cp + (size_t)bz * sC)[ci] = v;
        } else if (EPI == EPI_SILU) {
          ((_Float16*)Cp + (size_t)bz * sC)[ci] =
              (_Float16)(v / (1.f + expf(-v)));
        } else if (EPI == EPI_SCORES) {
          float s = v * 0.08838834764831845f;  // 1/sqrt(128)
          s = fmaxf(s, 0.f);
          s = (gc <= gr0 + r) ? s * s : 0.f;
          ((_Float16*)Cp + (size_t)bz * sC)[ci] = (_Float16)s;
        } else if (EPI == EPI_GATED) {  // gh = u * (attn@v)
          const _Float16* Ub = U + (size_t)bz * sC;
          ((_Float16*)Cp + (size_t)bz * sC)[ci] = (_Float16)((float)Ub[ci] * v);
        } else {  // EPI_RESID
          ((float*)Cp)[ci] += v;
        }
      }
    }
  }
}

__global__ void __launch_bounds__(256) ln_kernel(const float* __restrict__ x,
                                                 const float* __restrict__ g,
                                                 const float* __restrict__ b,
                                                 _Float16* __restrict__ out) {
  int row = blockIdx.x, tid = threadIdx.x;
  float4 v = ((const float4*)(x + (size_t)row * Dd))[tid];
  float s = v.x + v.y + v.z + v.w;
  float q = v.x * v.x + v.y * v.y + v.z * v.z + v.w * v.w;
#pragma unroll
  for (int off = 32; off > 0; off >>= 1) {
    s += __shfl_down(s, off, 64);
    q += __shfl_down(q, off, 64);
  }
  __shared__ float ss[4], sq[4];
  int lane = tid & 63, wv = tid >> 6;
  if (lane == 0) { ss[wv] = s; sq[wv] = q; }
  __syncthreads();
  s = ss[0] + ss[1] + ss[2] + ss[3];
  q = sq[0] + sq[1] + sq[2] + sq[3];
  float mu = s * (1.f / Dd);
  float var = q * (1.f / Dd) - mu * mu;
  float rs = rsqrtf(var + 1e-5f);
  float4 gg = ((const float4*)g)[tid];
  float4 bb = ((const float4*)b)[tid];
  f16x4 o;
  o[0] = (_Float16)((v.x - mu) * rs * gg.x + bb.x);
  o[1] = (_Float16)((v.y - mu) * rs * gg.y + bb.y);
  o[2] = (_Float16)((v.z - mu) * rs * gg.z + bb.z);
  o[3] = (_Float16)((v.w - mu) * rs * gg.w + bb.w);
  ((f16x4*)(out + (size_t)row * Dd))[tid] = o;
}

__global__ void embed_kernel(const int* __restrict__ toks,
                             const float* __restrict__ emb,
                             float* __restrict__ x) {
  int row = blockIdx.x, tid = threadIdx.x;
  long t = toks[row];
  ((float4*)(x + (size_t)row * Dd))[tid] =
      ((const float4*)(emb + (size_t)t * Dd))[tid];
}

__global__ void rope_table_kernel(float* __restrict__ cosT,
                                  float* __restrict__ sinT) {
  int idx = blockIdx.x * 256 + threadIdx.x;  // T*64
  int t = idx >> 6, i = idx & 63;
  float inv = powf(10000.f, (float)(2 * i) * (-1.f / 128.f));
  float a = (float)t * inv;
  cosT[idx] = cosf(a);
  sinT[idx] = sinf(a);
}

__global__ void rope_kernel(const float* __restrict__ pre,
                            _Float16* __restrict__ o16,
                            const float* __restrict__ cosT,
                            const float* __restrict__ sinT) {
  int row = blockIdx.x * 4 + threadIdx.y;
  int i = threadIdx.x;
  int z = blockIdx.y;
  const float* p = pre + (size_t)z * BT * Ss + (size_t)row * Ss;
  _Float16* o = o16 + (size_t)z * BT * Ss + (size_t)row * Ss;
  int t = row & (Tt - 1);
  float c = cosT[t * 64 + i], sn = sinT[t * 64 + i];
  float x1 = p[i], x2 = p[i + 64];
  o[i] = (_Float16)(x1 * c - x2 * sn);
  o[i + 64] = (_Float16)(x1 * sn + x2 * c);
}

// out(C x R) = transpose(in(R x C)), convert to f16.
template <typename TIn>
__global__ void transconv_kernel(const TIn* __restrict__ in,
                                 _Float16* __restrict__ out, int R, int C,
                                 long s_in, long s_out) {
  __shared__ float tile[64][65];
  in += (size_t)blockIdx.z * s_in;
  out += (size_t)blockIdx.z * s_out;
  int r0 = blockIdx.y * 64, c0 = blockIdx.x * 64;
  int tx = threadIdx.x & 63, ty = threadIdx.x >> 6;
#pragma unroll
  for (int p = 0; p < 16; p++) {
    int r = p * 4 + ty;
    tile[r][tx] = (float)in[(size_t)(r0 + r) * C + c0 + tx];
  }
  __syncthreads();
#pragma unroll
  for (int p = 0; p < 16; p++) {
    int r = p * 4 + ty;
    out[(size_t)(c0 + r) * R + r0 + tx] = (_Float16)tile[tx][r];
  }
}

extern "C" void kernel_launch(void* const* d_in, const int* in_sizes, int n_in,
                              void* d_out, int out_size, void* d_ws,
                              size_t ws_size, hipStream_t stream) {
  const int*   tokens = (const int*)d_in[0];
  const float* emb    = (const float*)d_in[1];
  const float* Wu     = (const float*)d_in[2];
  const float* Wv     = (const float*)d_in[3];
  const float* Wq     = (const float*)d_in[4];
  const float* Wk     = (const float*)d_in[5];
  const float* Wo     = (const float*)d_in[6];
  const float* ln_g   = (const float*)d_in[7];
  const float* ln_b   = (const float*)d_in[8];
  const float* lnf_g  = (const float*)d_in[9];
  const float* lnf_b  = (const float*)d_in[10];
  const float* Wlm    = (const float*)d_in[11];
  float* out = (float*)d_out;
  (void)in_sizes; (void)n_in; (void)out_size;

  char* wsp = (char*)d_ws;
  size_t off = 0;
  auto alloc = [&](size_t bytes) -> void* {
    void* p = wsp + off;
    off = (off + bytes + 255) & ~(size_t)255;
    return p;
  };

  float*    x     = (float*)alloc((size_t)BT * Dd * 4);
  _Float16* xn    = (_Float16*)alloc((size_t)BT * Dd * 2);
  _Float16* uvh   = (_Float16*)alloc((size_t)2 * BT * Ee * 2);
  _Float16* vT    = (_Float16*)alloc((size_t)Bz * Ee * Tt * 2);
  float*    qkpre = (float*)alloc((size_t)2 * BT * Ss * 4);
  _Float16* qkh   = (_Float16*)alloc((size_t)2 * BT * Ss * 2);
  _Float16* attn  = (_Float16*)alloc((size_t)Bz * Tt * Tt * 2);
  _Float16* gh    = (_Float16*)alloc((size_t)BT * Ee * 2);
  float*    cosT  = (float*)alloc((size_t)Tt * 64 * 4);
  float*    sinT  = (float*)alloc((size_t)Tt * 64 * 4);
  _Float16* WuvT  = (_Float16*)alloc((size_t)2 * Ll * Ee * Dd * 2);
  _Float16* WqkT  = (_Float16*)alloc((size_t)2 * Ll * Ss * Ee * 2);
  _Float16* WoT   = (_Float16*)alloc((size_t)Ll * Dd * Ee * 2);
  _Float16* WlmT  = (_Float16*)alloc((size_t)Vv * Dd * 2);
  if (off > ws_size) return;

  transconv_kernel<float><<<dim3(Ee / 64, Dd / 64, Ll), 256, 0, stream>>>(
      Wu, WuvT, Dd, Ee, (long)Dd * Ee, (long)Ee * Dd);
  transconv_kernel<float><<<dim3(Ee / 64, Dd / 64, Ll), 256, 0, stream>>>(
      Wv, WuvT + (size_t)Ll * Ee * Dd, Dd, Ee, (long)Dd * Ee, (long)Ee * Dd);
  transconv_kernel<float><<<dim3(Ss / 64, Ee / 64, Ll), 256, 0, stream>>>(
      Wq, WqkT, Ee, Ss, (long)Ee * Ss, (long)Ss * Ee);
  transconv_kernel<float><<<dim3(Ss / 64, Ee / 64, Ll), 256, 0, stream>>>(
      Wk, WqkT + (size_t)Ll * Ss * Ee, Ee, Ss, (long)Ee * Ss, (long)Ss * Ee);
  transconv_kernel<float><<<dim3(Dd / 64, Ee / 64, Ll), 256, 0, stream>>>(
      Wo, WoT, Ee, Dd, (long)Ee * Dd, (long)Dd * Ee);
  transconv_kernel<float><<<dim3(Vv / 64, Dd / 64, 1), 256, 0, stream>>>(
      Wlm, WlmT, Dd, Vv, 0, 0);

  rope_table_kernel<<<(Tt * 64) / 256, 256, 0, stream>>>(cosT, sinT);
  embed_kernel<<<BT, 256, 0, stream>>>(tokens, emb, x);

  for (int l = 0; l < Ll; l++) {
    ln_kernel<<<BT, 256, 0, stream>>>(x, ln_g + (size_t)l * Dd,
                                      ln_b + (size_t)l * Dd, xn);
    // u = silu(xn@Wu), v = silu(xn@Wv)  -- 256^2 8-phase kernel
    gemm256<EPI_SILU><<<dim3((BT / 256) * (Ee / 256), 1, 2), 512, 0, stream>>>(
        xn, 0, WuvT + (size_t)l * Ee * Dd, (long)Ll * Ee * Dd, (void*)uvh,
        (long)BT * Ee, BT, Ee, Dd, Dd, Dd, Ee);
    // q_pre = u@Wq, k_pre = v@Wk
    gemm_bt<EPI_F32><<<dim3(BT / BM, Ss / BN, 2), 256, 0, stream>>>(
        uvh, (long)BT * Ee, WqkT + (size_t)l * Ss * Ee, (long)Ll * Ss * Ee,
        (void*)qkpre, (long)BT * Ss, BT, Ss, Ee, Ee, Ee, Ss, 0, nullptr);
    rope_kernel<<<dim3(BT / 4, 2), dim3(64, 4), 0, stream>>>(qkpre, qkh, cosT,
                                                             sinT);
    transconv_kernel<_Float16><<<dim3(Ee / 64, Tt / 64, Bz), 256, 0, stream>>>(
        uvh + (size_t)BT * Ee, vT, Tt, Ee, (long)Tt * Ee, (long)Ee * Tt);
    // scores = relu(mask(q@k^T * scale))^2
    gemm_bt<EPI_SCORES><<<dim3(Tt / BM, Tt / BN, Bz), 256, 0, stream>>>(
        qkh, (long)Tt * Ss, qkh + (size_t)BT * Ss, (long)Tt * Ss, (void*)attn,
        (long)Tt * Tt, Tt, Tt, Ss, Ss, Ss, Tt, 0, nullptr);
    // gh = u * (attn @ v)   (gate fused into av epilogue)
    gemm_bt<EPI_GATED><<<dim3(Tt / BM, Ee / BN, Bz), 256, 0, stream>>>(
        attn, (long)Tt * Tt, vT, (long)Ee * Tt, (void*)gh, (long)Tt * Ee, Tt,
        Ee, Tt, Tt, Tt, Ee, 2, uvh);
    // x += gh @ Wo
    gemm_bt<EPI_RESID><<<dim3(BT / BM, Dd / BN, 1), 256, 0, stream>>>(
        gh, 0, WoT + (size_t)l * Dd * Ee, 0, (void*)x, 0, BT, Dd, Ee, Ee, Ee,
        Dd, 0, nullptr);
  }

  ln_kernel<<<BT, 256, 0, stream>>>(x, lnf_g, lnf_b, xn);
  // logits = xn @ Wlm   -- 256^2 8-phase kernel
  gemm256<EPI_F32><<<dim3((BT / 256) * (Vv / 256), 1, 1), 512, 0, stream>>>(
      xn, 0, WlmT, 0, (void*)out, 0, BT, Vv, Dd, Dd, Dd, Vv);
}